// Round 1
// baseline (2436.556 us; speedup 1.0000x reference)
//
#include <hip/hip_runtime.h>
#include <hip/hip_fp16.h>

#define HW   1600
#define NP1  1601
#define NPAD 1608          // padded row length (elements), 1608 % 8 == 0
#define NC   256
#define NB   8
#define MU_  (1.0f/3200.0f)
#define ITERS 100

// ---------------- K0: transpose A planes: fa[b][c][m] = A[b][c][m%40][m/40] ----
__global__ void k_transpose(const float* __restrict__ A, float* __restrict__ fa) {
  __shared__ float lds[1600];
  int plane = blockIdx.x;                       // b*NC + c
  const float* src = A + (size_t)plane * HW;
  float* dst = fa + (size_t)plane * HW;
  for (int p = threadIdx.x; p < HW; p += 256) lds[p] = src[p];
  __syncthreads();
  for (int q = threadIdx.x; q < HW; q += 256) dst[q] = lds[(q % 40) * 40 + q / 40];
}

// ---------------- K init: zero colsq/ot, b=1 (pads 0), a=0 ----------------
__global__ void k_init(float* colsq, float* avec, float* bvec, float* ot) {
  int idx = blockIdx.x * 256 + threadIdx.x;
  if (idx < NB * NPAD) {
    int j = idx % NPAD;
    bvec[idx] = (j <= HW) ? 1.0f : 0.0f;
    avec[idx] = 0.0f;
  }
  if (idx < NB * HW) colsq[idx] = 0.0f;
  if (idx < NB) ot[idx] = 0.0f;
}

// ---------------- GEMM: corr = fa^T fb, relu; MODE0: colsq, MODE1: write khat ----
#define BM 128
#define BN 128
#define BK 16

template<int MODE>
__global__ __launch_bounds__(256) void k_gemm(const float* __restrict__ fa,
                                              const float* __restrict__ fb,
                                              float* __restrict__ colsq,
                                              __half* __restrict__ khat,
                                              __half* __restrict__ khatT) {
  __shared__ float As[BK][BM];
  __shared__ float Bs[BK][BN];
  __shared__ __half Ts[BM][BN + 8];     // transpose staging (MODE1); cs overlay (MODE0)
  float* cs = (float*)&Ts[0][0];

  int b  = blockIdx.z;
  int m0 = blockIdx.y * BM;
  int n0 = blockIdx.x * BN;
  int tid = threadIdx.x;
  int tx = tid & 15, ty = tid >> 4;

  float acc[8][8];
#pragma unroll
  for (int r = 0; r < 8; ++r)
#pragma unroll
    for (int c = 0; c < 8; ++c) acc[r][c] = 0.f;

  const float* fab = fa + (size_t)b * NC * HW;
  const float* fbb = fb + (size_t)b * NC * HW;

  for (int k0 = 0; k0 < NC; k0 += BK) {
#pragma unroll
    for (int l = 0; l < 2; ++l) {
      int id = tid + l * 256;                 // 0..511
      int kk = id >> 5, mq = id & 31;
      int m = m0 + mq * 4;
      float4 v = make_float4(0.f, 0.f, 0.f, 0.f);
      if (m < HW) v = *(const float4*)(fab + (size_t)(k0 + kk) * HW + m);
      *(float4*)&As[kk][mq * 4] = v;
      int n = n0 + mq * 4;
      float4 w = make_float4(0.f, 0.f, 0.f, 0.f);
      if (n < HW) w = *(const float4*)(fbb + (size_t)(k0 + kk) * HW + n);
      *(float4*)&Bs[kk][mq * 4] = w;
    }
    __syncthreads();
#pragma unroll
    for (int kk = 0; kk < BK; ++kk) {
      float a[8], bb[8];
      *(float4*)&a[0]  = *(float4*)&As[kk][ty * 8];
      *(float4*)&a[4]  = *(float4*)&As[kk][ty * 8 + 4];
      *(float4*)&bb[0] = *(float4*)&Bs[kk][tx * 8];
      *(float4*)&bb[4] = *(float4*)&Bs[kk][tx * 8 + 4];
#pragma unroll
      for (int r = 0; r < 8; ++r)
#pragma unroll
        for (int c = 0; c < 8; ++c) acc[r][c] = fmaf(a[r], bb[c], acc[r][c]);
    }
    __syncthreads();
  }

#pragma unroll
  for (int r = 0; r < 8; ++r)
#pragma unroll
    for (int c = 0; c < 8; ++c) acc[r][c] = fmaxf(acc[r][c], 0.f);

  if (MODE == 0) {
    if (tid < BN) cs[tid] = 0.f;
    __syncthreads();
#pragma unroll
    for (int c = 0; c < 8; ++c) {
      float s = 0.f;
#pragma unroll
      for (int r = 0; r < 8; ++r) s += acc[r][c] * acc[r][c];
      atomicAdd(&cs[tx * 8 + c], s);
    }
    __syncthreads();
    if (tid < BN) {
      int n = n0 + tid;
      if (n < HW) atomicAdd(&colsq[b * HW + n], cs[tid]);
    }
  } else {
    float inv[8];
#pragma unroll
    for (int c = 0; c < 8; ++c) {
      int n = n0 + tx * 8 + c;
      inv[c] = (n < HW) ? 1.0f / (sqrtf(colsq[b * HW + n] + 1e-6f) * 16.0f) : 0.f;
    }
#pragma unroll
    for (int r = 0; r < 8; ++r) {
      int m = m0 + ty * 8 + r;
      __half hv[8];
#pragma unroll
      for (int c = 0; c < 8; ++c) {
        float sc = acc[r][c] * inv[c];
        __half h = __float2half(expf(sc));
        hv[c] = h;
        Ts[tx * 8 + c][ty * 8 + r] = h;       // stage transposed
      }
      if (m < HW && (n0 + tx * 8) < HW)
        *(uint4*)(khat + (size_t)(b * NP1 + m) * NPAD + n0 + tx * 8) = *(uint4*)hv;
    }
    __syncthreads();
#pragma unroll
    for (int r = 0; r < 8; ++r) {
      int j = n0 + ty * 8 + r;
      __half hv[8];
#pragma unroll
      for (int c = 0; c < 8; ++c) hv[c] = Ts[ty * 8 + r][tx * 8 + c];
      if (j < HW && (m0 + tx * 8) < HW)
        *(uint4*)(khatT + (size_t)(b * NP1 + j) * NPAD + m0 + tx * 8) = *(uint4*)hv;
    }
  }
}

// ---------------- K fill: bin row/col = E, pad cols = 0 (both matrices) --------
__global__ void k_fill(__half* khat, __half* khatT, const float* alpha) {
  float E = expf(alpha[0]);
  __half he = __float2half(E);
  __half hz = __float2half(0.f);
  int idx = blockIdx.x * 256 + threadIdx.x;          // over 2 * NB * NP1
  if (idx >= 2 * NB * NP1) return;
  __half* M = (idx < NB * NP1) ? khat : khatT;
  int t = idx % (NB * NP1);
  __half* row = M + (size_t)t * NPAD;
  int i = t % NP1;
  if (i < HW) {
    __half hv[8];
    hv[0] = he;
    for (int k = 1; k < 8; ++k) hv[k] = hz;
    *(uint4*)(row + HW) = *(uint4*)hv;               // cols 1600..1607
  } else {                                            // bin row: all E, pads 0
    for (int j = 0; j < NPAD; j += 8) {
      __half hv[8];
      for (int k = 0; k < 8; ++k) hv[k] = ((j + k) <= HW) ? he : hz;
      *(uint4*)(row + j) = *(uint4*)hv;
    }
  }
}

// ---------------- Sinkhorn half-iteration: vout = mu / (K vin), wave per row ---
__global__ __launch_bounds__(256) void k_sink(const __half* __restrict__ K,
                                              const float* __restrict__ vin,
                                              float* __restrict__ vout) {
  int wid = threadIdx.x >> 6;
  int lane = threadIdx.x & 63;
  int row = blockIdx.x * 4 + wid;
  if (row >= NB * NP1) return;
  int b = row / NP1, i = row % NP1;
  const __half* kr = K + (size_t)row * NPAD;
  const float* v = vin + (size_t)b * NPAD;
  float acc = 0.f;
  for (int c = lane; c < NPAD / 8; c += 64) {
    uint4 kk = *(const uint4*)(kr + c * 8);
    float4 v0 = *(const float4*)(v + c * 8);
    float4 v1 = *(const float4*)(v + c * 8 + 4);
    __half2 h0 = *(__half2*)&kk.x, h1 = *(__half2*)&kk.y;
    __half2 h2 = *(__half2*)&kk.z, h3 = *(__half2*)&kk.w;
    acc = fmaf(__low2float(h0),  v0.x, acc);
    acc = fmaf(__high2float(h0), v0.y, acc);
    acc = fmaf(__low2float(h1),  v0.z, acc);
    acc = fmaf(__high2float(h1), v0.w, acc);
    acc = fmaf(__low2float(h2),  v1.x, acc);
    acc = fmaf(__high2float(h2), v1.y, acc);
    acc = fmaf(__low2float(h3),  v1.z, acc);
    acc = fmaf(__high2float(h3), v1.w, acc);
  }
#pragma unroll
  for (int o = 32; o > 0; o >>= 1) acc += __shfl_xor(acc, o, 64);
  float mu = (i < HW) ? MU_ : 0.5f;
  if (lane == 0) vout[(size_t)b * NPAD + i] = mu / acc;
}

// ---------------- Epilogue: ot[b] = sum_{i,j<1600} a_i b_j K ln(K) -------------
__global__ __launch_bounds__(256) void k_ot(const __half* __restrict__ khat,
                                            const float* __restrict__ avec,
                                            const float* __restrict__ bvec,
                                            float* __restrict__ ot) {
  int wid = threadIdx.x >> 6;
  int lane = threadIdx.x & 63;
  int row = blockIdx.x * 4 + wid;
  if (row >= NB * HW) return;
  int b = row / HW, i = row % HW;
  const __half* kr = khat + (size_t)(b * NP1 + i) * NPAD;
  const float* bv = bvec + (size_t)b * NPAD;
  float acc = 0.f;
  for (int c = lane; c < HW / 8; c += 64) {          // cols 0..1599 only
    uint4 kk = *(const uint4*)(kr + c * 8);
    float4 v0 = *(const float4*)(bv + c * 8);
    float4 v1 = *(const float4*)(bv + c * 8 + 4);
    __half2 h0 = *(__half2*)&kk.x, h1 = *(__half2*)&kk.y;
    __half2 h2 = *(__half2*)&kk.z, h3 = *(__half2*)&kk.w;
    float f;
    f = __low2float(h0);  acc = fmaf(f * __logf(f), v0.x, acc);
    f = __high2float(h0); acc = fmaf(f * __logf(f), v0.y, acc);
    f = __low2float(h1);  acc = fmaf(f * __logf(f), v0.z, acc);
    f = __high2float(h1); acc = fmaf(f * __logf(f), v0.w, acc);
    f = __low2float(h2);  acc = fmaf(f * __logf(f), v1.x, acc);
    f = __high2float(h2); acc = fmaf(f * __logf(f), v1.y, acc);
    f = __low2float(h3);  acc = fmaf(f * __logf(f), v1.z, acc);
    f = __high2float(h3); acc = fmaf(f * __logf(f), v1.w, acc);
  }
#pragma unroll
  for (int o = 32; o > 0; o >>= 1) acc += __shfl_xor(acc, o, 64);
  if (lane == 0) atomicAdd(&ot[b], acc * avec[(size_t)b * NPAD + i]);
}

__global__ void k_final(const float* __restrict__ ot, float* __restrict__ out) {
  int b = threadIdx.x;
  if (b < NB) out[b] = expf(-3200.0f * ot[b]);
}

extern "C" void kernel_launch(void* const* d_in, const int* in_sizes, int n_in,
                              void* d_out, int out_size, void* d_ws, size_t ws_size,
                              hipStream_t stream) {
  const float* A     = (const float*)d_in[0];
  const float* Bf    = (const float*)d_in[1];
  const float* alpha = (const float*)d_in[2];
  float* out = (float*)d_out;

  char* ws = (char*)d_ws;
  size_t off = 0;
  auto alloc = [&](size_t bytes) -> void* {
    void* p = (void*)(ws + off);
    off += (bytes + 255) & ~(size_t)255;
    return p;
  };
  float*  fa    = (float*)alloc((size_t)NB * NC * HW * 4);          // 13.1 MB
  __half* khat  = (__half*)alloc((size_t)NB * NP1 * NPAD * 2);      // 41.2 MB
  __half* khatT = (__half*)alloc((size_t)NB * NP1 * NPAD * 2);      // 41.2 MB
  float*  colsq = (float*)alloc((size_t)NB * HW * 4);
  float*  avec  = (float*)alloc((size_t)NB * NPAD * 4);
  float*  bvec  = (float*)alloc((size_t)NB * NPAD * 4);
  float*  ot    = (float*)alloc((size_t)NB * 4);

  hipLaunchKernelGGL(k_init, dim3((NB * NPAD + 255) / 256), dim3(256), 0, stream,
                     colsq, avec, bvec, ot);
  hipLaunchKernelGGL(k_transpose, dim3(NB * NC), dim3(256), 0, stream, A, fa);

  dim3 gg((HW + BN - 1) / BN, (HW + BM - 1) / BM, NB);
  hipLaunchKernelGGL((k_gemm<0>), gg, dim3(256), 0, stream, fa, Bf, colsq, khat, khatT);
  hipLaunchKernelGGL((k_gemm<1>), gg, dim3(256), 0, stream, fa, Bf, colsq, khat, khatT);
  hipLaunchKernelGGL(k_fill, dim3((2 * NB * NP1 + 255) / 256), dim3(256), 0, stream,
                     khat, khatT, alpha);

  dim3 sg((NB * NP1 + 3) / 4);
  for (int it = 0; it < ITERS; ++it) {
    hipLaunchKernelGGL(k_sink, sg, dim3(256), 0, stream, khat,  bvec, avec);
    hipLaunchKernelGGL(k_sink, sg, dim3(256), 0, stream, khatT, avec, bvec);
  }

  hipLaunchKernelGGL(k_ot, dim3((NB * HW + 3) / 4), dim3(256), 0, stream,
                     khat, avec, bvec, ot);
  hipLaunchKernelGGL(k_final, dim3(1), dim3(64), 0, stream, ot, out);
}